// Round 2
// baseline (285.611 us; speedup 1.0000x reference)
//
#include <hip/hip_runtime.h>

namespace {
constexpr int MD = 4;
constexpr int BB = 8, CC = 128, HH = 96, WW = 192;
constexpr int TH = 4, TW = 64;
constexpr int KC = 8;                         // channels staged per LDS chunk
constexpr int NCHUNK = CC / KC;               // 16 chunks -> 32 barriers total
constexpr int NROWS = TH + 2 * MD;            // 12 staged rows
constexpr int ROWF  = 80;                     // floats staged per row
constexpr int LSTR  = 84;                     // padded LDS row stride (16B-aligned)
constexpr int F4_PER_ROW = ROWF / 4;          // 20
constexpr int F4_PER_CH  = NROWS * F4_PER_ROW;// 240
constexpr int NTHR = 192;
constexpr int PER_THR = KC * F4_PER_CH / NTHR;// 10 float4 staged per thread
}

__global__ __launch_bounds__(NTHR, 2)
void corr81(const float* __restrict__ in0,
            const float* __restrict__ in1,
            float* __restrict__ out)
{
    const int tid  = threadIdx.x;
    const int wv   = tid >> 6;          // wave 0..2 -> 3 displacement rows each
    const int lane = tid & 63;
    const int g    = lane >> 4;         // h-row within tile (0..3)
    const int q    = lane & 15;         // w-group: owns w0+q*4 .. +3

    const int w0 = blockIdx.x * TW;
    const int h0 = blockIdx.y * TH;
    const int b  = blockIdx.z;

    __shared__ float lds[KC][NROWS][LSTR];   // 32.25 KB

    const size_t plane = (size_t)HH * WW;
    const size_t img   = (size_t)CC * plane;
    const float* in1b  = in1 + (size_t)b * img;

    // Staging slots: idx -> (ch, row, col4); consecutive tids -> consecutive
    // float4 within a row (coalesced).
    int  soff[PER_THR];   // float offset within chunk-relative image
    int  loff[PER_THR];   // byte offset into lds
    bool sok[PER_THR];
    #pragma unroll
    for (int i = 0; i < PER_THR; ++i) {
        const int idx = tid + i * NTHR;
        const int ch  = idx / F4_PER_CH;
        const int rem = idx % F4_PER_CH;
        const int row = rem / F4_PER_ROW;
        const int col = (rem % F4_PER_ROW) * 4;
        const int grow = h0 - MD + row;
        const int gcol = w0 - 8 + col;
        sok[i]  = (grow >= 0 && grow < HH && gcol >= 0 && gcol < WW);
        soff[i] = ch * (int)plane + grow * WW + gcol;
        loff[i] = (int)(((ch * NROWS + row) * LSTR + col) * sizeof(float));
    }

    const float* pa = in0 + (size_t)b * img + (size_t)(h0 + g) * WW + (w0 + q * 4);

    float acc[3][9][4];
    #pragma unroll
    for (int rr = 0; rr < 3; ++rr)
        #pragma unroll
        for (int cc = 0; cc < 9; ++cc)
            #pragma unroll
            for (int j = 0; j < 4; ++j) acc[rr][cc][j] = 0.f;

    // prefetch chunk 0
    float4 stg[PER_THR];
    #pragma unroll
    for (int i = 0; i < PER_THR; ++i)
        stg[i] = sok[i] ? *(const float4*)(in1b + soff[i])
                        : make_float4(0.f, 0.f, 0.f, 0.f);

    for (int k = 0; k < NCHUNK; ++k) {
        __syncthreads();                      // readers of previous chunk done
        #pragma unroll
        for (int i = 0; i < PER_THR; ++i)
            *(float4*)((char*)lds + loff[i]) = stg[i];
        __syncthreads();

        if (k + 1 < NCHUNK) {                 // prefetch next chunk under compute
            const float* nb = in1b + (size_t)(k + 1) * KC * plane;
            #pragma unroll
            for (int i = 0; i < PER_THR; ++i)
                stg[i] = sok[i] ? *(const float4*)(nb + soff[i])
                                : make_float4(0.f, 0.f, 0.f, 0.f);
        }

        const float* pak = pa + (size_t)k * KC * plane;
        #pragma unroll
        for (int ch = 0; ch < KC; ++ch) {
            const float4 a = *(const float4*)(pak + (size_t)ch * plane);
            const float av[4] = {a.x, a.y, a.z, a.w};
            #pragma unroll
            for (int rr = 0; rr < 3; ++rr) {
                const int row = g + wv * 3 + rr;        // lds row = g + (r+4)
                const float* lrow = &lds[ch][row][q * 4];
                const float4 wA = *(const float4*)(lrow + 4);
                const float4 wB = *(const float4*)(lrow + 8);
                const float4 wC = *(const float4*)(lrow + 12);
                const float win[12] = {wA.x, wA.y, wA.z, wA.w,
                                       wB.x, wB.y, wB.z, wB.w,
                                       wC.x, wC.y, wC.z, wC.w};
                #pragma unroll
                for (int cc = 0; cc < 9; ++cc)
                    #pragma unroll
                    for (int j = 0; j < 4; ++j)
                        acc[rr][cc][j] = fmaf(av[j], win[cc + j], acc[rr][cc][j]);
            }
        }
    }

    const float scale = 1.0f / CC;
    float* ob = out + ((size_t)b * 81) * plane + (size_t)(h0 + g) * WW + (w0 + q * 4);
    #pragma unroll
    for (int rr = 0; rr < 3; ++rr) {
        const int dbase = (wv * 3 + rr) * 9;
        #pragma unroll
        for (int cc = 0; cc < 9; ++cc) {
            float4 o = make_float4(acc[rr][cc][0] * scale, acc[rr][cc][1] * scale,
                                   acc[rr][cc][2] * scale, acc[rr][cc][3] * scale);
            *(float4*)(ob + (size_t)(dbase + cc) * plane) = o;
        }
    }
}

extern "C" void kernel_launch(void* const* d_in, const int* in_sizes, int n_in,
                              void* d_out, int out_size, void* d_ws, size_t ws_size,
                              hipStream_t stream)
{
    const float* in0 = (const float*)d_in[0];
    const float* in1 = (const float*)d_in[1];
    float* out = (float*)d_out;
    dim3 grid(WW / TW, HH / TH, BB);   // 3 x 24 x 8 = 576 blocks
    corr81<<<grid, dim3(NTHR), 0, stream>>>(in0, in1, out);
}

// Round 3
// 197.267 us; speedup vs baseline: 1.4478x; 1.4478x over previous
//
#include <hip/hip_runtime.h>

namespace {
constexpr int MD  = 4;
constexpr int BB  = 8, CCH = 128, HH = 96, WW = 192;
constexpr int TH  = 16, TW = 48, WPT = 12;     // tile 16 x 48, 12 px/thread
constexpr int KC  = 4;                          // channels per LDS chunk
constexpr int NCHUNK = CCH / KC;                // 32 chunks, 32 barriers
constexpr int SROWS = 18;                       // staged rows per rrset block
constexpr int NJ  = 14;                         // logical f4 per row (56 floats)
constexpr int LJ  = 16;                         // padded f4 per row (XOR-safe)
constexpr int NTHR = 192;                       // 3 waves = one rrset
constexpr int F4C = SROWS * NJ;                 // 252 staged f4 per channel
constexpr int F4K = KC * F4C;                   // 1008 per chunk
constexpr int PER = (F4K + NTHR - 1) / NTHR;    // 6 slots/thread
}

__global__ __launch_bounds__(NTHR, 1)
void corr81(const float* __restrict__ in0,
            const float* __restrict__ in1,
            float* __restrict__ out)
{
    const int tid  = threadIdx.x;
    const int wv   = tid >> 6;            // wave 0..2 -> rr within rrset
    const int lane = tid & 63;
    const int g    = lane >> 2;           // h-row in tile (0..15)
    const int q    = lane & 3;            // w-group: owns w0+q*12 .. +11

    const int wt = blockIdx.x, ht = blockIdx.y, zz = blockIdx.z;
    const int b  = zz / 3, rs = zz % 3;   // rs = rrset (disp rows rs*3..rs*3+2)
    const int w0 = wt * TW, h0 = ht * TH;
    const int rr   = rs * 3 + wv;         // displacement row index 0..8 (r = rr-4)
    const int rmin = rs * 3 - 4;          // first staged row offset vs h0

    __shared__ float4 lds[2][KC][SROWS][LJ];    // 36.9 KB

    const size_t plane = (size_t)HH * WW;
    const size_t img   = (size_t)CCH * plane;
    const float* in1b  = in1 + (size_t)b * img;

    // ---- staging slot precompute: slot s -> (ch, row, j) ----
    int  soff[PER];  int ldst[PER];  bool sok[PER];
    #pragma unroll
    for (int i = 0; i < PER; ++i) {
        const int s   = tid + i * NTHR;          // < F4K except tail of i==5
        const int ch  = s / F4C;
        const int r2  = s % F4C;
        const int row = r2 / NJ;
        const int j   = r2 % NJ;
        const int hr  = h0 + rmin + row;
        const int wc  = w0 - 4 + 4 * j;          // always 4-aligned; f4 fully in/out
        sok[i]  = (s < F4K) && hr >= 0 && hr < HH && wc >= 0 && (wc + 3) < WW;
        soff[i] = ch * (int)plane + hr * WW + wc;
        const int js = (j & 8) | ((j ^ (row & 7)) & 7);   // XOR bank swizzle
        ldst[i] = (ch * SROWS + row) * LJ + js;
    }
    const bool svalid5 = (tid + 5 * NTHR) < F4K;  // only slot 5 can be invalid

    // window read slots (thread-constant, swizzled)
    const int rowidx = g + wv;                    // staged row for this thread
    int js_[5];
    #pragma unroll
    for (int k = 0; k < 5; ++k) {
        const int jl = 3 * q + k;
        js_[k] = (jl & 8) | ((jl ^ (rowidx & 7)) & 7);
    }

    const float* pa = in0 + (size_t)b * img + (size_t)(h0 + g) * WW + (w0 + q * WPT);

    float acc[9][WPT];
    #pragma unroll
    for (int cc = 0; cc < 9; ++cc)
        #pragma unroll
        for (int j = 0; j < WPT; ++j) acc[cc][j] = 0.f;

    // ---- prologue: fetch chunk 0 into regs ----
    float4 stg[PER];
    #pragma unroll
    for (int i = 0; i < PER; ++i)
        stg[i] = sok[i] ? *(const float4*)(in1b + soff[i])
                        : make_float4(0.f, 0.f, 0.f, 0.f);

    for (int t = 0; t < NCHUNK; ++t) {
        float4* bufp = &lds[t & 1][0][0][0];
        #pragma unroll
        for (int i = 0; i < PER - 1; ++i) bufp[ldst[i]] = stg[i];
        if (svalid5) bufp[ldst[PER - 1]] = stg[PER - 1];

        if (t + 1 < NCHUNK) {                    // issue next chunk early
            const float* nb = in1b + (size_t)(t + 1) * KC * plane;
            #pragma unroll
            for (int i = 0; i < PER; ++i)
                stg[i] = sok[i] ? *(const float4*)(nb + soff[i])
                                : make_float4(0.f, 0.f, 0.f, 0.f);
        }

        __syncthreads();                         // single barrier per chunk (safe:
                                                 // WAR on buf[t&1] is two barriers old)

        #pragma unroll
        for (int ch = 0; ch < KC; ++ch) {
            const float* pac = pa + (size_t)(t * KC + ch) * plane;
            const float4 a0 = *(const float4*)(pac + 0);
            const float4 a1 = *(const float4*)(pac + 4);
            const float4 a2 = *(const float4*)(pac + 8);
            const float av[WPT] = {a0.x, a0.y, a0.z, a0.w,
                                   a1.x, a1.y, a1.z, a1.w,
                                   a2.x, a2.y, a2.z, a2.w};
            const float4* rbase = &lds[t & 1][ch][rowidx][0];
            float wn[20];
            #pragma unroll
            for (int k = 0; k < 5; ++k) {
                const float4 w4 = rbase[js_[k]];
                wn[4 * k + 0] = w4.x; wn[4 * k + 1] = w4.y;
                wn[4 * k + 2] = w4.z; wn[4 * k + 3] = w4.w;
            }
            #pragma unroll
            for (int cc = 0; cc < 9; ++cc)
                #pragma unroll
                for (int j = 0; j < WPT; ++j)
                    acc[cc][j] = fmaf(av[j], wn[cc + j], acc[cc][j]);
        }
    }

    // ---- epilogue ----
    const float scale = 1.0f / CCH;
    float* ob = out + ((size_t)b * 81 + (size_t)rr * 9) * plane
                    + (size_t)(h0 + g) * WW + (w0 + q * WPT);
    #pragma unroll
    for (int cc = 0; cc < 9; ++cc) {
        float* oc = ob + (size_t)cc * plane;
        #pragma unroll
        for (int k = 0; k < 3; ++k) {
            float4 o = make_float4(acc[cc][4 * k + 0] * scale,
                                   acc[cc][4 * k + 1] * scale,
                                   acc[cc][4 * k + 2] * scale,
                                   acc[cc][4 * k + 3] * scale);
            *(float4*)(oc + 4 * k) = o;
        }
    }
}

extern "C" void kernel_launch(void* const* d_in, const int* in_sizes, int n_in,
                              void* d_out, int out_size, void* d_ws, size_t ws_size,
                              hipStream_t stream)
{
    const float* in0 = (const float*)d_in[0];
    const float* in1 = (const float*)d_in[1];
    float* out = (float*)d_out;
    dim3 grid(WW / TW, HH / TH, BB * 3);   // 4 x 6 x 24 = 576 blocks, 3 waves each
    corr81<<<grid, dim3(NTHR), 0, stream>>>(in0, in1, out);
}